// Round 12
// baseline (105.695 us; speedup 1.0000x reference)
//
#include <hip/hip_runtime.h>
#include <hip/hip_bf16.h>

// Problem constants
#define B_ROWS 4096
#define NN     8192
#define DD     128
#define NSPLIT 16           // column splits (= #cs blocks); merged across wn in LDS
#define TSTEPS 8            // 256 pair-cols per block / 32 per t-step
#define SPAD   264          // sPn row stride in u16 (256 + 8 pad: kills 4-way bank conflict)
#define CSHIFT 128.0f       // fixed logsumexp shift (log2 domain)

typedef __attribute__((ext_vector_type(8))) short s8v;   // 8 bf16 (4 VGPR)
typedef __attribute__((ext_vector_type(4))) float f4v;   // 4 f32
typedef __attribute__((ext_vector_type(2))) float f2v;
typedef __attribute__((ext_vector_type(4))) unsigned short u16x4;
typedef unsigned int u32;

static constexpr float SCALE_H = 1.6986436f;      // sqrt(2*log2(e)); folds /TEMP and log2e into the matmul
static constexpr float SCALE2  = 2.8853900818f;   // 2*log2(e)
static constexpr float LN2     = 0.6931471805599453f;

__device__ __forceinline__ float fast_exp2(float x) {
#if __has_builtin(__builtin_amdgcn_exp2f)
    return __builtin_amdgcn_exp2f(x);      // bare v_exp_f32
#else
    return exp2f(x);
#endif
}

// (1 - x^2) with mask folded in, rounded to bf16 bits
__device__ __forceinline__ unsigned short s2m_pack(float x, bool msk) {
    float s2 = msk ? 0.f : 1.f - x * x;    // s2m=0 => exp2(0*acc - 128) -> ~0
    union { __hip_bfloat16 h; unsigned short u; } cv;
    cv.h = __float2bfloat16(s2);
    return cv.u;
}

typedef __attribute__((address_space(1))) const u32 gu32;
typedef __attribute__((address_space(3))) u32 lu32;
__device__ __forceinline__ void gload_lds16(const void* g, void* l) {
    // async global->LDS, 16B/lane; dest = lds base + lane*16 (wave-uniform base)
    __builtin_amdgcn_global_load_lds((gu32*)g, (lu32*)l, 16, 0, 0);
}

// ---- kernel 1: fused bf16-prep + pos dot ----
__global__ void hpos_kernel(const float* __restrict__ hi, const float* __restrict__ hj,
                            __hip_bfloat16* __restrict__ hb, float* __restrict__ pos2) {
    int w = threadIdx.x >> 6, l = threadIdx.x & 63;
    int row = blockIdx.x * 4 + w;
    f2v a = ((const f2v*)(hi + (size_t)row * DD))[l];
    f2v b = ((const f2v*)(hj + (size_t)row * DD))[l];
    float d = a[0] * b[0] + a[1] * b[1];
    #pragma unroll
    for (int off = 32; off; off >>= 1) d += __shfl_xor(d, off, 64);
    if (l == 0) pos2[row] = SCALE2 * d;
    union { ushort2 u2; __hip_bfloat16 h[2]; } ua, ub;
    ua.h[0] = __float2bfloat16(a[0] * SCALE_H);
    ua.h[1] = __float2bfloat16(a[1] * SCALE_H);
    ub.h[0] = __float2bfloat16(b[0] * SCALE_H);
    ub.h[1] = __float2bfloat16(b[1] * SCALE_H);
    ((ushort2*)(hb + (size_t)row * DD))[l] = ua.u2;
    ((ushort2*)(hb + (size_t)(row + B_ROWS) * DD))[l] = ub.u2;
}

// ---- kernel 2: fused sim*S2 + masked fixed-shift sum-of-exp2 ----
// R10 skeleton (proven) with TSTEPS=8: 512-thr / 8-wave blocks (wm 0..3, wn 0..1),
// 64 pair-rows x 256 pair-cols, grid 1024 = 64 rb x 16 cs. B tiles dbuf via
// global_load_lds (linear dest, pre-swizzled source); plain __syncthreads
// 2-phase schedule; bf16 s2m panel (mask folded), rows padded to 264 u16.
__global__ __launch_bounds__(512, 4)
void main_kernel(const __hip_bfloat16* __restrict__ hb, const float* __restrict__ S,
                 float* __restrict__ ssplit) {
    __shared__ short ldsB[2][64][128];            // 2 x 16 KB B tiles (swizzled)
    __shared__ unsigned short sPn[64][SPAD];      // 33.8 KB s2m panel (bf16, padded)

    const int tid = threadIdx.x;
    const int l  = tid & 63;
    const int w  = tid >> 6;             // 0..7
    const int wm = w >> 1, wn = w & 1;
    const int rb = blockIdx.x & 63;
    const int cs = blockIdx.x >> 6;
    const int r0 = rb * 64 + wm * 16;    // wave pair-row base
    const int c0 = cs * 256;             // block pair-col base
    const int lc = l & 15;               // frag row/col within 16
    const int lk = l >> 4;               // k-group

    const s8v* hb8 = (const s8v*)hb;     // 16 x s8v per row of 128 bf16

#define STAGE(BUF, T) do {                                                        \
    _Pragma("unroll")                                                             \
    for (int i = 0; i < 2; i++) {                                                 \
        const int seg  = w * 2 + i;        /* 0..15 */                            \
        const int lrw  = seg * 4 + lk;     /* local row 0..63 */                  \
        const int grow = c0 + (T) * 32 + ((lrw < 32) ? lrw : (lrw - 32 + B_ROWS));\
        const int sc16 = lc ^ (lrw & 7);   /* source pre-swizzle */               \
        gload_lds16((const char*)hb + ((size_t)grow << 8) + (sc16 << 4),          \
                    (char*)&ldsB[BUF][seg * 4][0]);                               \
    }                                                                             \
} while (0)

    // prologue: stage B tile 0 (async), stage S panel in 2 reg-reusing passes
    STAGE(0, 0);

    const int lr = tid >> 5;             // 0..15
    const int cb = (tid & 31) * 4;       // 0..124
    #pragma unroll
    for (int ch = 0; ch < 2; ch++) {
        const int colb = ch * 128 + cb;
        const float* gS = S + (size_t)(rb * 64 + lr) * B_ROWS + c0 + colb;
        f4v sv[4];
        #pragma unroll
        for (int k = 0; k < 4; k++)
            sv[k] = *(const f4v*)(gS + (size_t)(k * 16) * B_ROWS);
        const int grw0 = rb * 64 + lr;       // global pair-row of sv[0]
        const int gcb  = c0 + colb;          // global pair-col base
        #pragma unroll
        for (int k = 0; k < 4; k++) {
            u16x4 p;
            #pragma unroll
            for (int e = 0; e < 4; e++)
                p[e] = s2m_pack(sv[k][e], gcb + e == grw0 + k * 16);
            *(u16x4*)&sPn[lr + k * 16][colb] = p;
        }
    }

    s8v afr[2][4];
    #pragma unroll
    for (int fm = 0; fm < 2; fm++) {
        int ar = r0 + lc + fm * B_ROWS;
        #pragma unroll
        for (int kk = 0; kk < 4; kk++)
            afr[fm][kk] = hb8[ar * 16 + kk * 4 + lk];
    }
    __syncthreads();   // B tile 0 + panel + afr ready

    float ssum[2][4];
    #pragma unroll
    for (int fm = 0; fm < 2; fm++)
        #pragma unroll
        for (int r = 0; r < 4; r++) ssum[fm][r] = 0.f;

    // loop-invariant ds_read addrs; +BUF*16384 / +8192 are immediate offsets
    const char* bp[4];
    {
        const char* bb = (const char*)ldsB + (wn * 16 + lc) * 256;
        #pragma unroll
        for (int kk = 0; kk < 4; kk++)
            bp[kk] = bb + (((kk * 4 + lk) ^ (lc & 7)) << 4);
    }

#define COMPUTE(BUF, T) do {                                                      \
    f4v acc[2][2];                                                                \
    _Pragma("unroll")                                                             \
    for (int fm = 0; fm < 2; fm++)                                                \
        _Pragma("unroll")                                                         \
        for (int fh = 0; fh < 2; fh++) acc[fm][fh] = f4v{0.f, 0.f, 0.f, 0.f};     \
    _Pragma("unroll")                                                             \
    for (int kk = 0; kk < 4; kk++) {                                              \
        s8v bf0 = *(const s8v*)(bp[kk] + ((BUF) * 16384));                        \
        s8v bf1 = *(const s8v*)(bp[kk] + ((BUF) * 16384 + 8192));                 \
        _Pragma("unroll")                                                         \
        for (int fm = 0; fm < 2; fm++) {                                          \
            acc[fm][0] = __builtin_amdgcn_mfma_f32_16x16x32_bf16(                 \
                afr[fm][kk], bf0, acc[fm][0], 0, 0, 0);                           \
            acc[fm][1] = __builtin_amdgcn_mfma_f32_16x16x32_bf16(                 \
                afr[fm][kk], bf1, acc[fm][1], 0, 0, 0);                           \
        }                                                                         \
    }                                                                             \
    const int pcol = (T) * 32 + wn * 16 + lc;                                     \
    _Pragma("unroll")                                                             \
    for (int r = 0; r < 4; r++) {                                                 \
        const int prow = wm * 16 + lk * 4 + r;                                    \
        const float s2 = __uint_as_float(((u32)sPn[prow][pcol]) << 16);           \
        _Pragma("unroll")                                                         \
        for (int fm = 0; fm < 2; fm++) {                                          \
            float e0 = fast_exp2(fmaf(acc[fm][0][r], s2, -CSHIFT));               \
            float e1 = fast_exp2(fmaf(acc[fm][1][r], s2, -CSHIFT));               \
            ssum[fm][r] += e0 + e1;                                               \
        }                                                                         \
    }                                                                             \
} while (0)

    // 2-phase pipeline: stage next tile, compute current, barrier
    STAGE(1, 1); COMPUTE(0, 0); __syncthreads();
    STAGE(0, 2); COMPUTE(1, 1); __syncthreads();
    STAGE(1, 3); COMPUTE(0, 2); __syncthreads();
    STAGE(0, 4); COMPUTE(1, 3); __syncthreads();
    STAGE(1, 5); COMPUTE(0, 4); __syncthreads();
    STAGE(0, 6); COMPUTE(1, 5); __syncthreads();
    STAGE(1, 7); COMPUTE(0, 6); __syncthreads();
                 COMPUTE(1, 7);

#undef STAGE
#undef COMPUTE

    // pure-sum reduce over the 16 lanes holding each row, merge wn via LDS
    // merge scratch aliased into ldsB[0] (dead: last read was COMPUTE(0,6),
    // all waves past it via the final barrier; COMPUTE(1,7) reads ldsB[1])
    float* sexb = (float*)&ldsB[0][0][0];   // [wn][fm][rho] = 256 floats
    #pragma unroll
    for (int fm = 0; fm < 2; fm++) {
        #pragma unroll
        for (int r = 0; r < 4; r++) {
            float ss = ssum[fm][r];
            #pragma unroll
            for (int off = 1; off < 16; off <<= 1)
                ss += __shfl_xor(ss, off, 64);
            if (lc == 0) {
                int rho = wm * 16 + lk * 4 + r;   // block-local pair-row 0..63
                sexb[wn * 128 + fm * 64 + rho] = ss;
            }
        }
    }
    __syncthreads();
    if (tid < 128) {
        int fm = tid >> 6, rho = tid & 63;
        float ss = sexb[fm * 64 + rho] + sexb[128 + fm * 64 + rho];
        int gr = rb * 64 + rho + fm * B_ROWS;
        ssplit[cs * NN + gr] = ss;
    }
}

// ---- kernel 3a: per-row split sum + lse, block partial sums (parallel) ----
__global__ __launch_bounds__(256)
void reduce_kernel(const float* __restrict__ ssplit, const float* __restrict__ pos2,
                   float* __restrict__ partial) {
    __shared__ float red[256];
    const int n = blockIdx.x * 256 + threadIdx.x;   // n < 8192
    float p = pos2[n & (B_ROWS - 1)];
    float Ssum = fast_exp2(p - CSHIFT);             // pos logit seeds the sum
    #pragma unroll
    for (int sp = 0; sp < NSPLIT; sp++)
        Ssum += ssplit[sp * NN + n];
    red[threadIdx.x] = (CSHIFT + log2f(Ssum)) - p;  // log2 units
    __syncthreads();
    for (int st = 128; st; st >>= 1) {
        if (threadIdx.x < st) red[threadIdx.x] += red[threadIdx.x + st];
        __syncthreads();
    }
    if (threadIdx.x == 0) partial[blockIdx.x] = red[0];
}

// ---- kernel 3b: deterministic final sum over 32 partials ----
__global__ void final_kernel(const float* __restrict__ partial, float* __restrict__ out) {
    if (threadIdx.x == 0) {
        float s = 0.f;
        #pragma unroll
        for (int i = 0; i < 32; i++) s += partial[i];
        out[0] = s * (LN2 / (float)NN);
    }
}

extern "C" void kernel_launch(void* const* d_in, const int* in_sizes, int n_in,
                              void* d_out, int out_size, void* d_ws, size_t ws_size,
                              hipStream_t stream) {
    (void)in_sizes; (void)n_in; (void)out_size; (void)ws_size;
    const float* hi = (const float*)d_in[0];
    const float* hj = (const float*)d_in[1];
    const float* S  = (const float*)d_in[2];

    char* ws = (char*)d_ws;
    __hip_bfloat16* hb = (__hip_bfloat16*)ws;                        // 2 MB
    float* pos2   = (float*)(ws + 2097152);                          // 16 KB
    float* ssplit = (float*)(ws + 2097152 + 16384);                  // 512 KB (16 splits)
    float* partial= (float*)(ws + 2097152 + 16384 + 524288);         // 128 B

    hpos_kernel<<<1024, 256, 0, stream>>>(hi, hj, hb, pos2);
    main_kernel<<<1024, 512, 0, stream>>>(hb, S, ssplit);
    reduce_kernel<<<32, 256, 0, stream>>>(ssplit, pos2, partial);
    final_kernel<<<1, 64, 0, stream>>>(partial, (float*)d_out);
}

// Round 13
// 52.475 us; speedup vs baseline: 2.0142x; 2.0142x over previous
//
#include <hip/hip_runtime.h>
#include <hip/hip_bf16.h>

// Problem constants
#define B_ROWS 4096
#define NN     8192
#define DD     128
#define NSPLIT 32           // column splits (= #cs blocks); merged across wn in LDS
#define TSTEPS 4            // 128 pair-cols per block / 32 per t-step
#define SPAD   132          // sPn row stride in u16: 264B=66 words; 4 rows = 264 words
                            // = 8 mod 32 -> lk-groups on disjoint bank octets
#define CSHIFT 128.0f       // fixed logsumexp shift (log2 domain)

typedef __attribute__((ext_vector_type(8))) short s8v;   // 8 bf16 (4 VGPR)
typedef __attribute__((ext_vector_type(4))) float f4v;   // 4 f32
typedef __attribute__((ext_vector_type(2))) float f2v;
typedef __attribute__((ext_vector_type(4))) unsigned short u16x4;
typedef unsigned int u32;

static constexpr float SCALE_H = 1.6986436f;      // sqrt(2*log2(e)); folds /TEMP and log2e into the matmul
static constexpr float SCALE2  = 2.8853900818f;   // 2*log2(e)
static constexpr float LN2     = 0.6931471805599453f;

__device__ __forceinline__ float fast_exp2(float x) {
#if __has_builtin(__builtin_amdgcn_exp2f)
    return __builtin_amdgcn_exp2f(x);      // bare v_exp_f32
#else
    return exp2f(x);
#endif
}

// (1 - x^2) with mask folded in, rounded to bf16 bits
__device__ __forceinline__ unsigned short s2m_pack(float x, bool msk) {
    float s2 = msk ? 0.f : 1.f - x * x;    // s2m=0 => exp2(0*acc - 128) -> ~0
    union { __hip_bfloat16 h; unsigned short u; } cv;
    cv.h = __float2bfloat16(s2);
    return cv.u;
}

typedef __attribute__((address_space(1))) const u32 gu32;
typedef __attribute__((address_space(3))) u32 lu32;
__device__ __forceinline__ void gload_lds16(const void* g, void* l) {
    // async global->LDS, 16B/lane; dest = lds base + lane*16 (wave-uniform base)
    __builtin_amdgcn_global_load_lds((gu32*)g, (lu32*)l, 16, 0, 0);
}

// ---- kernel 1: fused bf16-prep + pos dot ----
__global__ void hpos_kernel(const float* __restrict__ hi, const float* __restrict__ hj,
                            __hip_bfloat16* __restrict__ hb, float* __restrict__ pos2) {
    int w = threadIdx.x >> 6, l = threadIdx.x & 63;
    int row = blockIdx.x * 4 + w;
    f2v a = ((const f2v*)(hi + (size_t)row * DD))[l];
    f2v b = ((const f2v*)(hj + (size_t)row * DD))[l];
    float d = a[0] * b[0] + a[1] * b[1];
    #pragma unroll
    for (int off = 32; off; off >>= 1) d += __shfl_xor(d, off, 64);
    if (l == 0) pos2[row] = SCALE2 * d;
    union { ushort2 u2; __hip_bfloat16 h[2]; } ua, ub;
    ua.h[0] = __float2bfloat16(a[0] * SCALE_H);
    ua.h[1] = __float2bfloat16(a[1] * SCALE_H);
    ub.h[0] = __float2bfloat16(b[0] * SCALE_H);
    ub.h[1] = __float2bfloat16(b[1] * SCALE_H);
    ((ushort2*)(hb + (size_t)row * DD))[l] = ua.u2;
    ((ushort2*)(hb + (size_t)(row + B_ROWS) * DD))[l] = ub.u2;
}

// ---- kernel 2: fused sim*S2 + masked fixed-shift sum-of-exp2 ----
// R10 skeleton (proven stable: 64 VGPR, no spill): 512-thr / 8-wave blocks
// (wm 0..3, wn 0..1), 64 pair-rows x 128 pair-cols, grid 2048 = 64 rb x 32 cs.
// B tiles dbuf via global_load_lds (linear dest, pre-swizzled source); plain
// __syncthreads 2-phase schedule; bf16 s2m panel with mask folded in.
// R12 delta: sPn rows padded to 132 u16 -> panel reads bank-conflict-free.
__global__ __launch_bounds__(512, 4)
void main_kernel(const __hip_bfloat16* __restrict__ hb, const float* __restrict__ S,
                 float* __restrict__ ssplit) {
    __shared__ short ldsB[2][64][128];            // 2 x 16 KB B tiles (swizzled)
    __shared__ unsigned short sPn[64][SPAD];      // 16.5 KB s2m panel (bf16, padded)

    const int tid = threadIdx.x;
    const int l  = tid & 63;
    const int w  = tid >> 6;             // 0..7
    const int wm = w >> 1, wn = w & 1;
    const int rb = blockIdx.x & 63;
    const int cs = blockIdx.x >> 6;
    const int r0 = rb * 64 + wm * 16;    // wave pair-row base
    const int c0 = cs * 128;             // block pair-col base
    const int lc = l & 15;               // frag row/col within 16
    const int lk = l >> 4;               // k-group

    const s8v* hb8 = (const s8v*)hb;     // 16 x s8v per row of 128 bf16

#define STAGE(BUF, T) do {                                                        \
    _Pragma("unroll")                                                             \
    for (int i = 0; i < 2; i++) {                                                 \
        const int seg  = w * 2 + i;        /* 0..15 */                            \
        const int lrw  = seg * 4 + lk;     /* local row 0..63 */                  \
        const int grow = c0 + (T) * 32 + ((lrw < 32) ? lrw : (lrw - 32 + B_ROWS));\
        const int sc16 = lc ^ (lrw & 7);   /* source pre-swizzle */               \
        gload_lds16((const char*)hb + ((size_t)grow << 8) + (sc16 << 4),          \
                    (char*)&ldsB[BUF][seg * 4][0]);                               \
    }                                                                             \
} while (0)

    // prologue: stage B tile 0 (async), load S rows to regs, load A frags
    STAGE(0, 0);

    f4v sv[4];
    const int lr = tid >> 5;             // 0..15
    const int cb = (tid & 31) * 4;       // 0..124
    {
        const float* gS = S + (size_t)(rb * 64 + lr) * B_ROWS + c0 + cb;
        #pragma unroll
        for (int k = 0; k < 4; k++)
            sv[k] = *(const f4v*)(gS + (size_t)(k * 16) * B_ROWS);
    }

    s8v afr[2][4];
    #pragma unroll
    for (int fm = 0; fm < 2; fm++) {
        int ar = r0 + lc + fm * B_ROWS;
        #pragma unroll
        for (int kk = 0; kk < 4; kk++)
            afr[fm][kk] = hb8[ar * 16 + kk * 4 + lk];
    }

    // transform: s2m = (col==row) ? 0 : 1 - S^2, bf16-pack, write panel
    {
        const int grw0 = rb * 64 + lr;       // global pair-row of sv[0]
        const int gcb  = c0 + cb;            // global pair-col base
        #pragma unroll
        for (int k = 0; k < 4; k++) {
            u16x4 p;
            #pragma unroll
            for (int e = 0; e < 4; e++)
                p[e] = s2m_pack(sv[k][e], gcb + e == grw0 + k * 16);
            *(u16x4*)&sPn[lr + k * 16][cb] = p;
        }
    }
    __syncthreads();   // B tile 0 + panel + afr ready

    float ssum[2][4];
    #pragma unroll
    for (int fm = 0; fm < 2; fm++)
        #pragma unroll
        for (int r = 0; r < 4; r++) ssum[fm][r] = 0.f;

    // loop-invariant ds_read addrs; +BUF*16384 / +8192 are immediate offsets
    const char* bp[4];
    {
        const char* bb = (const char*)ldsB + (wn * 16 + lc) * 256;
        #pragma unroll
        for (int kk = 0; kk < 4; kk++)
            bp[kk] = bb + (((kk * 4 + lk) ^ (lc & 7)) << 4);
    }

#define COMPUTE(BUF, T) do {                                                      \
    f4v acc[2][2];                                                                \
    _Pragma("unroll")                                                             \
    for (int fm = 0; fm < 2; fm++)                                                \
        _Pragma("unroll")                                                         \
        for (int fh = 0; fh < 2; fh++) acc[fm][fh] = f4v{0.f, 0.f, 0.f, 0.f};     \
    _Pragma("unroll")                                                             \
    for (int kk = 0; kk < 4; kk++) {                                              \
        s8v bf0 = *(const s8v*)(bp[kk] + ((BUF) * 16384));                        \
        s8v bf1 = *(const s8v*)(bp[kk] + ((BUF) * 16384 + 8192));                 \
        _Pragma("unroll")                                                         \
        for (int fm = 0; fm < 2; fm++) {                                          \
            acc[fm][0] = __builtin_amdgcn_mfma_f32_16x16x32_bf16(                 \
                afr[fm][kk], bf0, acc[fm][0], 0, 0, 0);                           \
            acc[fm][1] = __builtin_amdgcn_mfma_f32_16x16x32_bf16(                 \
                afr[fm][kk], bf1, acc[fm][1], 0, 0, 0);                           \
        }                                                                         \
    }                                                                             \
    const int pcol = (T) * 32 + wn * 16 + lc;                                     \
    _Pragma("unroll")                                                             \
    for (int r = 0; r < 4; r++) {                                                 \
        const int prow = wm * 16 + lk * 4 + r;                                    \
        const float s2 = __uint_as_float(((u32)sPn[prow][pcol]) << 16);           \
        _Pragma("unroll")                                                         \
        for (int fm = 0; fm < 2; fm++) {                                          \
            float e0 = fast_exp2(fmaf(acc[fm][0][r], s2, -CSHIFT));               \
            float e1 = fast_exp2(fmaf(acc[fm][1][r], s2, -CSHIFT));               \
            ssum[fm][r] += e0 + e1;                                               \
        }                                                                         \
    }                                                                             \
} while (0)

    // 2-phase pipeline: stage next tile, compute current, barrier
    STAGE(1, 1); COMPUTE(0, 0); __syncthreads();
    STAGE(0, 2); COMPUTE(1, 1); __syncthreads();
    STAGE(1, 3); COMPUTE(0, 2); __syncthreads();
                 COMPUTE(1, 3);

#undef STAGE
#undef COMPUTE

    // pure-sum reduce over the 16 lanes holding each row, merge wn via LDS
    // merge scratch aliased into ldsB[0] (dead after COMPUTE(0,2) + barrier;
    // COMPUTE(1,3) reads only ldsB[1])
    float* sexb = (float*)&ldsB[0][0][0];   // [wn][fm][rho] = 256 floats
    #pragma unroll
    for (int fm = 0; fm < 2; fm++) {
        #pragma unroll
        for (int r = 0; r < 4; r++) {
            float ss = ssum[fm][r];
            #pragma unroll
            for (int off = 1; off < 16; off <<= 1)
                ss += __shfl_xor(ss, off, 64);
            if (lc == 0) {
                int rho = wm * 16 + lk * 4 + r;   // block-local pair-row 0..63
                sexb[wn * 128 + fm * 64 + rho] = ss;
            }
        }
    }
    __syncthreads();
    if (tid < 128) {
        int fm = tid >> 6, rho = tid & 63;
        float ss = sexb[fm * 64 + rho] + sexb[128 + fm * 64 + rho];
        int gr = rb * 64 + rho + fm * B_ROWS;
        ssplit[cs * NN + gr] = ss;
    }
}

// ---- kernel 3a: per-row split sum + lse, block partial sums (parallel) ----
__global__ __launch_bounds__(256)
void reduce_kernel(const float* __restrict__ ssplit, const float* __restrict__ pos2,
                   float* __restrict__ partial) {
    __shared__ float red[256];
    const int n = blockIdx.x * 256 + threadIdx.x;   // n < 8192
    float p = pos2[n & (B_ROWS - 1)];
    float Ssum = fast_exp2(p - CSHIFT);             // pos logit seeds the sum
    #pragma unroll
    for (int sp = 0; sp < NSPLIT; sp++)
        Ssum += ssplit[sp * NN + n];
    red[threadIdx.x] = (CSHIFT + log2f(Ssum)) - p;  // log2 units
    __syncthreads();
    for (int st = 128; st; st >>= 1) {
        if (threadIdx.x < st) red[threadIdx.x] += red[threadIdx.x + st];
        __syncthreads();
    }
    if (threadIdx.x == 0) partial[blockIdx.x] = red[0];
}

// ---- kernel 3b: deterministic final sum over 32 partials ----
__global__ void final_kernel(const float* __restrict__ partial, float* __restrict__ out) {
    if (threadIdx.x == 0) {
        float s = 0.f;
        #pragma unroll
        for (int i = 0; i < 32; i++) s += partial[i];
        out[0] = s * (LN2 / (float)NN);
    }
}

extern "C" void kernel_launch(void* const* d_in, const int* in_sizes, int n_in,
                              void* d_out, int out_size, void* d_ws, size_t ws_size,
                              hipStream_t stream) {
    (void)in_sizes; (void)n_in; (void)out_size; (void)ws_size;
    const float* hi = (const float*)d_in[0];
    const float* hj = (const float*)d_in[1];
    const float* S  = (const float*)d_in[2];

    char* ws = (char*)d_ws;
    __hip_bfloat16* hb = (__hip_bfloat16*)ws;                        // 2 MB
    float* pos2   = (float*)(ws + 2097152);                          // 16 KB
    float* ssplit = (float*)(ws + 2097152 + 16384);                  // 1 MB (32 splits)
    float* partial= (float*)(ws + 2097152 + 16384 + 1048576);        // 128 B

    hpos_kernel<<<1024, 256, 0, stream>>>(hi, hj, hb, pos2);
    main_kernel<<<2048, 512, 0, stream>>>(hb, S, ssplit);
    reduce_kernel<<<32, 256, 0, stream>>>(ssplit, pos2, partial);
    final_kernel<<<1, 64, 0, stream>>>(partial, (float*)d_out);
}